// Round 11
// baseline (236.415 us; speedup 1.0000x reference)
//
#include <hip/hip_runtime.h>

#define NN 10000      // nodes

typedef __attribute__((ext_vector_type(8))) short short8;
typedef __attribute__((ext_vector_type(4))) float f32x4;
typedef __attribute__((ext_vector_type(8))) _Float16 h16x8;
typedef __attribute__((ext_vector_type(4))) _Float16 h16x4;

__device__ __forceinline__ ushort f2b(float f) {
    union { float f; uint32_t u; } v; v.f = f;
    uint32_t u = v.u;
    return (ushort)((u + 0x7fffu + ((u >> 16) & 1u)) >> 16);
}
__device__ __forceinline__ uint packbf(float a, float b) {
    return (uint)f2b(a) | ((uint)f2b(b) << 16);
}
__device__ __forceinline__ float blo(uint u) {
    union { uint u; float f; } v; v.u = u << 16; return v.f;
}
__device__ __forceinline__ float bhi(uint u) {
    union { uint u; float f; } v; v.u = u & 0xffff0000u; return v.f;
}

// ---------------------------------------------------------------------------
// CSR build (R9-proven: simple counts + parallel hierarchical scan; R10's
// bucketed variant reverted -- null result, more work).
// ---------------------------------------------------------------------------
__global__ __launch_bounds__(256) void count_dst(const int* __restrict__ dst,
                                                 int* __restrict__ counts, int E) {
    int i = blockIdx.x * 256 + threadIdx.x;
    if (i < E) atomicAdd(&counts[dst[i]], 1);
}

__global__ __launch_bounds__(256) void scan_local(const int* __restrict__ counts,
                                                  int* __restrict__ lpref,
                                                  int* __restrict__ bsum, int n) {
    __shared__ int tmp[256];
    int t = threadIdx.x, b = blockIdx.x;
    int i = b * 256 + t;
    int c = (i < n) ? counts[i] : 0;
    tmp[t] = c;
    __syncthreads();
    for (int off = 1; off < 256; off <<= 1) {
        int v = (t >= off) ? tmp[t - off] : 0;
        __syncthreads();
        tmp[t] += v;
        __syncthreads();
    }
    if (i < n) lpref[i] = tmp[t] - c;          // exclusive local prefix
    if (t == 255) bsum[b] = tmp[255];          // block total
}

__global__ __launch_bounds__(256) void scan_apply(const int* __restrict__ counts,
                                                  const int* __restrict__ lpref,
                                                  const int* __restrict__ bsum,
                                                  int* __restrict__ offsets,
                                                  int* __restrict__ cursor,
                                                  float* __restrict__ inv_cnt, int n) {
    __shared__ int sbase;
    int t = threadIdx.x, b = blockIdx.x;
    if (t == 0) {
        int s = 0;
        for (int j = 0; j < b; j++) s += bsum[j];   // <=40 independent loads
        sbase = s;
    }
    __syncthreads();
    int i = b * 256 + t;
    if (i < n) {
        int c = counts[i];
        int o = sbase + lpref[i];
        offsets[i] = o;
        cursor[i]  = o;
        inv_cnt[i] = 1.0f / fmaxf((float)c, 1.0f);
    }
}

__global__ __launch_bounds__(256) void scatter_edges(const int* __restrict__ src,
                                                     const int* __restrict__ dst,
                                                     int* __restrict__ cursor,
                                                     int* __restrict__ sorted_src, int E) {
    int i = blockIdx.x * 256 + threadIdx.x;
    if (i < E) {
        int p = atomicAdd(&cursor[dst[i]], 1);
        sorted_src[p] = src[i];
    }
}

// ---------------------------------------------------------------------------
// Single fused fp32->bf16 conversion kernel + counts zeroing (R7-proven).
// ---------------------------------------------------------------------------
__global__ __launch_bounds__(256) void cvt_all(const float* __restrict__ x,
                                               const float* __restrict__ Wl0,
                                               const float* __restrict__ Wr0,
                                               const float* __restrict__ Wl1,
                                               const float* __restrict__ Wr1,
                                               const float* __restrict__ Wl2,
                                               const float* __restrict__ Wr2,
                                               ushort* __restrict__ xbuf,
                                               ushort* __restrict__ Wc0,
                                               ushort* __restrict__ Wc1,
                                               ushort* __restrict__ Wc2,
                                               int* __restrict__ counts) {
    int i = blockIdx.x * 256 + threadIdx.x;
    const float* src;
    ushort* dst;
    if (i < 1280000) {
        int idx = i * 4;
        src = x + idx;
        dst = xbuf + idx;
    } else if (i < 1411072) {
        int j = (i - 1280000) * 4;
        int row = j >> 9, col = j & 511;
        src = (row < 512) ? (Wl0 + (size_t)row * 512 + col)
                          : (Wr0 + (size_t)(row - 512) * 512 + col);
        dst = Wc0 + j;
    } else if (i < 1542144) {
        int j = (i - 1411072) * 4;
        int row = j >> 9, col = j & 511;
        src = (row < 512) ? (Wl1 + (size_t)row * 512 + col)
                          : (Wr1 + (size_t)(row - 512) * 512 + col);
        dst = Wc1 + j;
    } else if (i < 1607680) {
        int j = (i - 1542144) * 4;
        int row = j >> 9, col = j & 511;
        src = (row < 256) ? (Wl2 + (size_t)row * 512 + col)
                          : (Wr2 + (size_t)(row - 256) * 512 + col);
        dst = Wc2 + j;
    } else if (i < 1610180) {
        int t = i - 1607680;
        int4 z = {0, 0, 0, 0};
        *(int4*)(counts + t * 4) = z;
        return;
    } else {
        return;
    }
    float4 v = *(const float4*)src;
    uint2 p;
    p.x = packbf(v.x, v.y);
    p.y = packbf(v.z, v.w);
    *(uint2*)dst = p;
}

// ---------------------------------------------------------------------------
// bf16 MFMA NT-GEMM, split output (R9-proven: dbuf + XCD swizzle + T4
// counted-vmcnt). NEW: T5 s_setprio(1) around the MFMA cluster -- the
// counted-vmcnt loop has the {load-issuing vs MFMA-entering} wave role
// split that is T5's prerequisite (m218b).
// ---------------------------------------------------------------------------
__global__ __launch_bounds__(256) void gemm_split(const ushort* __restrict__ A,
                                                  const ushort* __restrict__ B,
                                                  ushort* __restrict__ G,
                                                  _Float16* __restrict__ R,
                                                  int M, int dout) {
    __shared__ ushort Asl[2][128 * 32];   // 16 KB
    __shared__ ushort Bsl[2][128 * 32];   // 16 KB
    const int tid  = threadIdx.x;
    const int w    = tid >> 6;
    const int lane = tid & 63;

    const int nbx = gridDim.x, nby = gridDim.y;
    const int nwg = nbx * nby;
    const int id  = blockIdx.y * nbx + blockIdx.x;
    const int qq  = nwg >> 3, rr = nwg & 7;
    const int xcd = id & 7, blk = id >> 3;
    const int swzid = (xcd < rr ? xcd * (qq + 1) : rr * (qq + 1) + (xcd - rr) * qq) + blk;
    const int bx = swzid % nbx, by = swzid / nbx;

    const int bm = by * 128, bn = bx * 128;
    const int wm = (w & 1) * 64, wn = (w >> 1) * 64;
    const int row16 = lane & 15, q = lane >> 4;

    f32x4 acc[4][4];
#pragma unroll
    for (int i = 0; i < 4; i++)
#pragma unroll
        for (int j = 0; j < 4; j++) acc[i][j] = (f32x4){0.f, 0.f, 0.f, 0.f};

    const int sc_r = lane >> 2;
    const int sc_s = lane & 3;
    const int koff = sc_s ^ ((sc_r >> 1) & 3);
    const int swz  = (row16 >> 1) & 3;

    auto stage = [&](int buf, int k0) {
#pragma unroll
        for (int c = 0; c < 2; c++) {
            int chunk = w * 2 + c;
            int rloc  = chunk * 16 + sc_r;
            int growA = bm + rloc; growA = growA < M ? growA : M - 1;
            const ushort* gpA = A + (size_t)growA * 512 + k0 + koff * 8;
            __builtin_amdgcn_global_load_lds(
                (const __attribute__((address_space(1))) uint32_t*)gpA,
                (__attribute__((address_space(3))) uint32_t*)&Asl[buf][chunk * 512],
                16, 0, 0);
            const ushort* gpB = B + (size_t)(bn + rloc) * 512 + k0 + koff * 8;
            __builtin_amdgcn_global_load_lds(
                (const __attribute__((address_space(1))) uint32_t*)gpB,
                (__attribute__((address_space(3))) uint32_t*)&Bsl[buf][chunk * 512],
                16, 0, 0);
        }
    };

    const int NT = 512 / 32;   // 16 K-steps
    stage(0, 0);
    asm volatile("s_waitcnt vmcnt(0)" ::: "memory");
    __builtin_amdgcn_sched_barrier(0);
    __builtin_amdgcn_s_barrier();
    int cur = 0;

    for (int t = 0; t < NT; ++t) {
        const bool pref = (t + 1 < NT);
        if (pref) {
            stage(cur ^ 1, (t + 1) * 32);
            // current tile's 4 loads are the oldest: <=4 outstanding means
            // they are done; the 4 prefetch loads remain in flight.
            asm volatile("s_waitcnt vmcnt(4)" ::: "memory");
        } else {
            asm volatile("s_waitcnt vmcnt(0)" ::: "memory");
        }
        __builtin_amdgcn_sched_barrier(0);
        __builtin_amdgcn_s_barrier();   // all waves' tile-t LDS writes visible

        short8 af[4], bfr[4];
        int s = q ^ swz;
#pragma unroll
        for (int i = 0; i < 4; i++) {
            int r = wm + i * 16 + row16;
            af[i] = *(const short8*)&Asl[cur][r * 32 + s * 8];
        }
#pragma unroll
        for (int j = 0; j < 4; j++) {
            int rn = wn + j * 16 + row16;
            bfr[j] = *(const short8*)&Bsl[cur][rn * 32 + s * 8];
        }
        __builtin_amdgcn_s_setprio(1);
#pragma unroll
        for (int i = 0; i < 4; i++)
#pragma unroll
            for (int j = 0; j < 4; j++)
                acc[i][j] = __builtin_amdgcn_mfma_f32_16x16x32_bf16(
                    af[i], bfr[j], acc[i][j], 0, 0, 0);
        __builtin_amdgcn_s_setprio(0);

        __builtin_amdgcn_sched_barrier(0);
        __builtin_amdgcn_s_barrier();   // no vmcnt drain (T4)
        cur ^= 1;
    }

    // C/D layout: col = lane&15, row = (lane>>4)*4 + reg  [m89-verified]
    const bool isR = (bn >= dout);
#pragma unroll
    for (int i = 0; i < 4; i++) {
#pragma unroll
        for (int r2 = 0; r2 < 4; r2++) {
            int row = bm + wm + i * 16 + q * 4 + r2;
            if (row < M) {
                if (isR) {
                    _Float16* Rp = R + (size_t)row * dout + (bn - dout) + wn + row16;
#pragma unroll
                    for (int j = 0; j < 4; j++)
                        Rp[j * 16] = (_Float16)acc[i][j][r2];
                } else {
                    ushort* Gp = G + (size_t)row * dout + bn + wn + row16;
#pragma unroll
                    for (int j = 0; j < 4; j++)
                        Gp[j * 16] = f2b(acc[i][j][r2]);
                }
            }
        }
    }
}

// ---------------------------------------------------------------------------
// Fused neighbor mean + R + bias + L2-normalize + ReLU (R4-proven body).
// NEW: R/bias loads issued BEFORE the gather loop (issue-early, T14-lite) --
// their HBM/L2 latency hides under the long gather phase.
// ---------------------------------------------------------------------------
template <int DOUT, bool FINAL>
__global__ __launch_bounds__(256) void aggfin(const ushort* __restrict__ G,
                                              const _Float16* __restrict__ R,
                                              const float* __restrict__ bias,
                                              const int* __restrict__ offsets,
                                              const int* __restrict__ counts,
                                              const int* __restrict__ sorted_src,
                                              const float* __restrict__ inv_cnt,
                                              ushort* __restrict__ xnext,
                                              float* __restrict__ outf, int n) {
    constexpr int PL = DOUT / 64;    // floats per lane: 8 (512) or 4 (256)
    int wave = threadIdx.x >> 6;
    int lane = threadIdx.x & 63;
    int node = blockIdx.x * 4 + wave;
    if (node >= n) return;
    int start = offsets[node];
    int cnt   = counts[node];
    float inv = inv_cnt[node];

    // early independent loads: R (fp16) + bias; latency hides under gather
    const _Float16* Rp = R + (size_t)node * DOUT + lane * PL;
    const float* Bp = bias + lane * PL;
    float rv[PL], bv[PL];
    if constexpr (PL == 8) {
        h16x8 hv = *(const h16x8*)Rp;
#pragma unroll
        for (int k = 0; k < PL; k++) rv[k] = (float)hv[k];
    } else {
        h16x4 hv = *(const h16x4*)Rp;
#pragma unroll
        for (int k = 0; k < PL; k++) rv[k] = (float)hv[k];
    }
#pragma unroll
    for (int k = 0; k < PL; k += 4) {
        float4 b4 = *(const float4*)(Bp + k);
        bv[k + 0] = b4.x; bv[k + 1] = b4.y; bv[k + 2] = b4.z; bv[k + 3] = b4.w;
    }

    float acc[PL];
#pragma unroll
    for (int k = 0; k < PL; k++) acc[k] = 0.f;

    if constexpr (DOUT == 512) {
        const uint* gp = (const uint*)G + lane * 4;   // row stride 256 uints
#define ACC8(v) do { \
        acc[0] += blo(v.x); acc[1] += bhi(v.x); \
        acc[2] += blo(v.y); acc[3] += bhi(v.y); \
        acc[4] += blo(v.z); acc[5] += bhi(v.z); \
        acc[6] += blo(v.w); acc[7] += bhi(v.w); } while (0)
        int e = 0;
        for (; e + 8 <= cnt; e += 8) {
            uint4 vv[8];
#pragma unroll
            for (int u = 0; u < 8; u++) {
                int s0 = sorted_src[start + e + u];
                vv[u] = *(const uint4*)(gp + (size_t)s0 * 256);
            }
#pragma unroll
            for (int u = 0; u < 8; u++) ACC8(vv[u]);
        }
        for (; e < cnt; e++) {
            int s0 = sorted_src[start + e];
            uint4 v0 = *(const uint4*)(gp + (size_t)s0 * 256);
            ACC8(v0);
        }
#undef ACC8
    } else {
        const uint* gp = (const uint*)G + lane * 2;   // row stride 128 uints
#define ACC4(v) do { \
        acc[0] += blo(v.x); acc[1] += bhi(v.x); \
        acc[2] += blo(v.y); acc[3] += bhi(v.y); } while (0)
        int e = 0;
        for (; e + 8 <= cnt; e += 8) {
            uint2 vv[8];
#pragma unroll
            for (int u = 0; u < 8; u++) {
                int s0 = sorted_src[start + e + u];
                vv[u] = *(const uint2*)(gp + (size_t)s0 * 128);
            }
#pragma unroll
            for (int u = 0; u < 8; u++) ACC4(vv[u]);
        }
        for (; e < cnt; e++) {
            int s0 = sorted_src[start + e];
            uint2 v0 = *(const uint2*)(gp + (size_t)s0 * 128);
            ACC4(v0);
        }
#undef ACC4
    }

    float v[PL];
#pragma unroll
    for (int k = 0; k < PL; k++) v[k] = acc[k] * inv + rv[k] + bv[k];

    float ss = 0.f;
#pragma unroll
    for (int k = 0; k < PL; k++) ss += v[k] * v[k];
#pragma unroll
    for (int m = 32; m >= 1; m >>= 1) ss += __shfl_xor(ss, m, 64);
    float scale = 1.0f / fmaxf(sqrtf(ss), 1e-12f);

    if constexpr (FINAL) {
        float* Op = outf + (size_t)node * DOUT + lane * PL;
#pragma unroll
        for (int k = 0; k < PL; k += 4) {
            float4 o;
            o.x = fmaxf(v[k + 0] * scale, 0.f);
            o.y = fmaxf(v[k + 1] * scale, 0.f);
            o.z = fmaxf(v[k + 2] * scale, 0.f);
            o.w = fmaxf(v[k + 3] * scale, 0.f);
            *(float4*)(Op + k) = o;
        }
    } else {
        // DOUT == 512: 8 bf16 = 16B per lane
        uint4 o;
        float r0 = fmaxf(v[0] * scale, 0.f), r1 = fmaxf(v[1] * scale, 0.f);
        float r2 = fmaxf(v[2] * scale, 0.f), r3 = fmaxf(v[3] * scale, 0.f);
        float r4 = fmaxf(v[4] * scale, 0.f), r5 = fmaxf(v[5] * scale, 0.f);
        float r6 = fmaxf(v[6] * scale, 0.f), r7 = fmaxf(v[7] * scale, 0.f);
        o.x = packbf(r0, r1); o.y = packbf(r2, r3);
        o.z = packbf(r4, r5); o.w = packbf(r6, r7);
        *(uint4*)(xnext + (size_t)node * 512 + lane * 8) = o;
    }
}

// ---------------------------------------------------------------------------
extern "C" void kernel_launch(void* const* d_in, const int* in_sizes, int n_in,
                              void* d_out, int out_size, void* d_ws, size_t ws_size,
                              hipStream_t stream) {
    const float* x    = (const float*)d_in[0];
    const int*   edge = (const int*)d_in[1];     // [2, E]: src row then dst row
    const float* Wl0  = (const float*)d_in[2];
    const float* b0   = (const float*)d_in[3];
    const float* Wr0  = (const float*)d_in[4];
    const float* Wl1  = (const float*)d_in[5];
    const float* b1   = (const float*)d_in[6];
    const float* Wr1  = (const float*)d_in[7];
    const float* Wl2  = (const float*)d_in[8];
    const float* b2   = (const float*)d_in[9];
    const float* Wr2  = (const float*)d_in[10];

    const int E = in_sizes[1] / 2;

    // Workspace layout (bytes), all 256-aligned
    char* ws = (char*)d_ws;
    int*      counts  = (int*)(ws + 0);              // 40000
    int*      offsets = (int*)(ws + 40960);
    int*      cursor  = (int*)(ws + 81920);
    float*    invc    = (float*)(ws + 122880);
    int*      sorted  = (int*)(ws + 163840);         // 640000
    ushort*   Wc0     = (ushort*)(ws + 819200);      // 1048576
    ushort*   Wc1     = (ushort*)(ws + 1867776);     // 1048576
    ushort*   Wc2     = (ushort*)(ws + 2916352);     // 524288
    ushort*   xbuf    = (ushort*)(ws + 3440640);     // 10240000
    ushort*   Gbuf    = (ushort*)(ws + 13680640);    // 10240000
    _Float16* Rbuf    = (_Float16*)(ws + 23920640);  // 10240000
    int*      lpref   = (int*)(ws + 34160640);       // 40960
    int*      bsum    = (int*)(ws + 34201600);       // 256
    // end: 34201856 bytes

    // ---- bf16 conversions + counts zeroing (single fused launch, first) ----
    cvt_all<<<(1610180 + 255) / 256, 256, 0, stream>>>(x, Wl0, Wr0, Wl1, Wr1, Wl2, Wr2,
                                                       xbuf, Wc0, Wc1, Wc2, counts);

    // ---- CSR build (parallel hierarchical scan) ----
    const int nsb = (NN + 255) / 256;   // 40 scan blocks
    count_dst<<<(E + 255) / 256, 256, 0, stream>>>(edge + E, counts, E);
    scan_local<<<nsb, 256, 0, stream>>>(counts, lpref, bsum, NN);
    scan_apply<<<nsb, 256, 0, stream>>>(counts, lpref, bsum, offsets, cursor, invc, NN);
    scatter_edges<<<(E + 255) / 256, 256, 0, stream>>>(edge, edge + E, cursor, sorted, E);

    const int gyM = (NN + 127) / 128;   // 79
    const int gb  = (NN + 3) / 4;       // 2500

    // ---- layer 0 ----
    gemm_split<<<dim3(8, gyM), 256, 0, stream>>>(xbuf, Wc0, Gbuf, Rbuf, NN, 512);
    aggfin<512, false><<<gb, 256, 0, stream>>>(Gbuf, Rbuf, b0, offsets, counts,
                                               sorted, invc, xbuf, nullptr, NN);
    // ---- layer 1 ----
    gemm_split<<<dim3(8, gyM), 256, 0, stream>>>(xbuf, Wc1, Gbuf, Rbuf, NN, 512);
    aggfin<512, false><<<gb, 256, 0, stream>>>(Gbuf, Rbuf, b1, offsets, counts,
                                               sorted, invc, xbuf, nullptr, NN);
    // ---- layer 2 (dout=256, final fp32 out) ----
    gemm_split<<<dim3(4, gyM), 256, 0, stream>>>(xbuf, Wc2, Gbuf, Rbuf, NN, 256);
    aggfin<256, true><<<gb, 256, 0, stream>>>(Gbuf, Rbuf, b2, offsets, counts,
                                              sorted, invc, nullptr, (float*)d_out, NN);
}

// Round 12
// 233.378 us; speedup vs baseline: 1.0130x; 1.0130x over previous
//
#include <hip/hip_runtime.h>

#define NN 10000      // nodes

typedef __attribute__((ext_vector_type(8))) short short8;
typedef __attribute__((ext_vector_type(4))) float f32x4;
typedef __attribute__((ext_vector_type(8))) _Float16 h16x8;
typedef __attribute__((ext_vector_type(4))) _Float16 h16x4;

__device__ __forceinline__ ushort f2b(float f) {
    union { float f; uint32_t u; } v; v.f = f;
    uint32_t u = v.u;
    return (ushort)((u + 0x7fffu + ((u >> 16) & 1u)) >> 16);
}
__device__ __forceinline__ uint packbf(float a, float b) {
    return (uint)f2b(a) | ((uint)f2b(b) << 16);
}
__device__ __forceinline__ float blo(uint u) {
    union { uint u; float f; } v; v.u = u << 16; return v.f;
}
__device__ __forceinline__ float bhi(uint u) {
    union { uint u; float f; } v; v.u = u & 0xffff0000u; return v.f;
}

// ---------------------------------------------------------------------------
// CSR build (R7-proven: parallel hierarchical scan)
// ---------------------------------------------------------------------------
__global__ __launch_bounds__(256) void count_dst(const int* __restrict__ dst,
                                                 int* __restrict__ counts, int E) {
    int i = blockIdx.x * 256 + threadIdx.x;
    if (i < E) atomicAdd(&counts[dst[i]], 1);
}

__global__ __launch_bounds__(256) void scan_local(const int* __restrict__ counts,
                                                  int* __restrict__ lpref,
                                                  int* __restrict__ bsum, int n) {
    __shared__ int tmp[256];
    int t = threadIdx.x, b = blockIdx.x;
    int i = b * 256 + t;
    int c = (i < n) ? counts[i] : 0;
    tmp[t] = c;
    __syncthreads();
    for (int off = 1; off < 256; off <<= 1) {
        int v = (t >= off) ? tmp[t - off] : 0;
        __syncthreads();
        tmp[t] += v;
        __syncthreads();
    }
    if (i < n) lpref[i] = tmp[t] - c;          // exclusive local prefix
    if (t == 255) bsum[b] = tmp[255];          // block total
}

__global__ __launch_bounds__(256) void scan_apply(const int* __restrict__ counts,
                                                  const int* __restrict__ lpref,
                                                  const int* __restrict__ bsum,
                                                  int* __restrict__ offsets,
                                                  int* __restrict__ cursor,
                                                  float* __restrict__ inv_cnt, int n) {
    __shared__ int sbase;
    int t = threadIdx.x, b = blockIdx.x;
    if (t == 0) {
        int s = 0;
        for (int j = 0; j < b; j++) s += bsum[j];   // <=40 independent loads
        sbase = s;
    }
    __syncthreads();
    int i = b * 256 + t;
    if (i < n) {
        int c = counts[i];
        int o = sbase + lpref[i];
        offsets[i] = o;
        cursor[i]  = o;
        inv_cnt[i] = 1.0f / fmaxf((float)c, 1.0f);
    }
}

__global__ __launch_bounds__(256) void scatter_edges(const int* __restrict__ src,
                                                     const int* __restrict__ dst,
                                                     int* __restrict__ cursor,
                                                     int* __restrict__ sorted_src, int E) {
    int i = blockIdx.x * 256 + threadIdx.x;
    if (i < E) {
        int p = atomicAdd(&cursor[dst[i]], 1);
        sorted_src[p] = src[i];
    }
}

// ---------------------------------------------------------------------------
// Single fused fp32->bf16 conversion kernel + counts zeroing (R7-proven).
// ---------------------------------------------------------------------------
__global__ __launch_bounds__(256) void cvt_all(const float* __restrict__ x,
                                               const float* __restrict__ Wl0,
                                               const float* __restrict__ Wr0,
                                               const float* __restrict__ Wl1,
                                               const float* __restrict__ Wr1,
                                               const float* __restrict__ Wl2,
                                               const float* __restrict__ Wr2,
                                               ushort* __restrict__ xbuf,
                                               ushort* __restrict__ Wc0,
                                               ushort* __restrict__ Wc1,
                                               ushort* __restrict__ Wc2,
                                               int* __restrict__ counts) {
    int i = blockIdx.x * 256 + threadIdx.x;
    const float* src;
    ushort* dst;
    if (i < 1280000) {
        int idx = i * 4;
        src = x + idx;
        dst = xbuf + idx;
    } else if (i < 1411072) {
        int j = (i - 1280000) * 4;
        int row = j >> 9, col = j & 511;
        src = (row < 512) ? (Wl0 + (size_t)row * 512 + col)
                          : (Wr0 + (size_t)(row - 512) * 512 + col);
        dst = Wc0 + j;
    } else if (i < 1542144) {
        int j = (i - 1411072) * 4;
        int row = j >> 9, col = j & 511;
        src = (row < 512) ? (Wl1 + (size_t)row * 512 + col)
                          : (Wr1 + (size_t)(row - 512) * 512 + col);
        dst = Wc1 + j;
    } else if (i < 1607680) {
        int j = (i - 1542144) * 4;
        int row = j >> 9, col = j & 511;
        src = (row < 256) ? (Wl2 + (size_t)row * 512 + col)
                          : (Wr2 + (size_t)(row - 256) * 512 + col);
        dst = Wc2 + j;
    } else if (i < 1610180) {
        int t = i - 1607680;
        int4 z = {0, 0, 0, 0};
        *(int4*)(counts + t * 4) = z;
        return;
    } else {
        return;
    }
    float4 v = *(const float4*)src;
    uint2 p;
    p.x = packbf(v.x, v.y);
    p.y = packbf(v.z, v.w);
    *(uint2*)dst = p;
}

// ---------------------------------------------------------------------------
// bf16 MFMA NT-GEMM, split output: C[M, 2*dout] = A[M,512] * B[2*dout,512]^T.
// Columns [0,dout) -> G (bf16); [dout,2*dout) -> R (fp16).
// R7 structure (dbuf + XCD swizzle) + T4 counted-vmcnt sync (R9-proven).
// Per K-step: stage(next, 4 loads/wave) -> s_waitcnt vmcnt(4) (current
// tile's loads -- the oldest -- complete; prefetch stays IN FLIGHT) ->
// sched_barrier -> raw s_barrier -> ds_read+MFMA -> raw s_barrier (no
// vmcnt drain). Removes the end-of-step vmcnt(0) drain (m233's 72% stall;
// m218: counted-vs-drain0 = +38-73%).
// Race analysis: pre-compute barrier publishes all waves' tile-t LDS
// writes (each waited vmcnt(4) first); end barrier separates compute(t)
// ds_reads (data-dep complete) from stage(t+2) overwrites.
// ---------------------------------------------------------------------------
__global__ __launch_bounds__(256) void gemm_split(const ushort* __restrict__ A,
                                                  const ushort* __restrict__ B,
                                                  ushort* __restrict__ G,
                                                  _Float16* __restrict__ R,
                                                  int M, int dout) {
    __shared__ ushort Asl[2][128 * 32];   // 16 KB
    __shared__ ushort Bsl[2][128 * 32];   // 16 KB
    const int tid  = threadIdx.x;
    const int w    = tid >> 6;
    const int lane = tid & 63;

    const int nbx = gridDim.x, nby = gridDim.y;
    const int nwg = nbx * nby;
    const int id  = blockIdx.y * nbx + blockIdx.x;
    const int qq  = nwg >> 3, rr = nwg & 7;
    const int xcd = id & 7, blk = id >> 3;
    const int swzid = (xcd < rr ? xcd * (qq + 1) : rr * (qq + 1) + (xcd - rr) * qq) + blk;
    const int bx = swzid % nbx, by = swzid / nbx;

    const int bm = by * 128, bn = bx * 128;
    const int wm = (w & 1) * 64, wn = (w >> 1) * 64;
    const int row16 = lane & 15, q = lane >> 4;

    f32x4 acc[4][4];
#pragma unroll
    for (int i = 0; i < 4; i++)
#pragma unroll
        for (int j = 0; j < 4; j++) acc[i][j] = (f32x4){0.f, 0.f, 0.f, 0.f};

    const int sc_r = lane >> 2;
    const int sc_s = lane & 3;
    const int koff = sc_s ^ ((sc_r >> 1) & 3);
    const int swz  = (row16 >> 1) & 3;

    auto stage = [&](int buf, int k0) {
#pragma unroll
        for (int c = 0; c < 2; c++) {
            int chunk = w * 2 + c;
            int rloc  = chunk * 16 + sc_r;
            int growA = bm + rloc; growA = growA < M ? growA : M - 1;
            const ushort* gpA = A + (size_t)growA * 512 + k0 + koff * 8;
            __builtin_amdgcn_global_load_lds(
                (const __attribute__((address_space(1))) uint32_t*)gpA,
                (__attribute__((address_space(3))) uint32_t*)&Asl[buf][chunk * 512],
                16, 0, 0);
            const ushort* gpB = B + (size_t)(bn + rloc) * 512 + k0 + koff * 8;
            __builtin_amdgcn_global_load_lds(
                (const __attribute__((address_space(1))) uint32_t*)gpB,
                (__attribute__((address_space(3))) uint32_t*)&Bsl[buf][chunk * 512],
                16, 0, 0);
        }
    };

    const int NT = 512 / 32;   // 16 K-steps
    stage(0, 0);               // 4 loads/wave in flight
    asm volatile("s_waitcnt vmcnt(0)" ::: "memory");
    __builtin_amdgcn_sched_barrier(0);
    __builtin_amdgcn_s_barrier();
    int cur = 0;

    for (int t = 0; t < NT; ++t) {
        const bool pref = (t + 1 < NT);
        if (pref) {
            stage(cur ^ 1, (t + 1) * 32);
            // current tile's 4 loads are the oldest: <=4 outstanding means
            // they are done; the 4 prefetch loads remain in flight.
            asm volatile("s_waitcnt vmcnt(4)" ::: "memory");
        } else {
            asm volatile("s_waitcnt vmcnt(0)" ::: "memory");
        }
        __builtin_amdgcn_sched_barrier(0);
        __builtin_amdgcn_s_barrier();   // all waves' tile-t LDS writes visible

        short8 af[4], bfr[4];
        int s = q ^ swz;
#pragma unroll
        for (int i = 0; i < 4; i++) {
            int r = wm + i * 16 + row16;
            af[i] = *(const short8*)&Asl[cur][r * 32 + s * 8];
        }
#pragma unroll
        for (int j = 0; j < 4; j++) {
            int rn = wn + j * 16 + row16;
            bfr[j] = *(const short8*)&Bsl[cur][rn * 32 + s * 8];
        }
#pragma unroll
        for (int i = 0; i < 4; i++)
#pragma unroll
            for (int j = 0; j < 4; j++)
                acc[i][j] = __builtin_amdgcn_mfma_f32_16x16x32_bf16(
                    af[i], bfr[j], acc[i][j], 0, 0, 0);

        // end barrier: separates this step's ds_reads (complete via data
        // deps) from next iteration's stage overwrite. NO vmcnt drain.
        __builtin_amdgcn_sched_barrier(0);
        __builtin_amdgcn_s_barrier();
        cur ^= 1;
    }

    // C/D layout: col = lane&15, row = (lane>>4)*4 + reg  [m89-verified]
    const bool isR = (bn >= dout);
#pragma unroll
    for (int i = 0; i < 4; i++) {
#pragma unroll
        for (int r2 = 0; r2 < 4; r2++) {
            int row = bm + wm + i * 16 + q * 4 + r2;
            if (row < M) {
                if (isR) {
                    _Float16* Rp = R + (size_t)row * dout + (bn - dout) + wn + row16;
#pragma unroll
                    for (int j = 0; j < 4; j++)
                        Rp[j * 16] = (_Float16)acc[i][j][r2];
                } else {
                    ushort* Gp = G + (size_t)row * dout + bn + wn + row16;
#pragma unroll
                    for (int j = 0; j < 4; j++)
                        Gp[j * 16] = f2b(acc[i][j][r2]);
                }
            }
        }
    }
}

// ---------------------------------------------------------------------------
// Fused neighbor mean + R + bias + L2-normalize + ReLU (R4-proven, unchanged).
// ---------------------------------------------------------------------------
template <int DOUT, bool FINAL>
__global__ __launch_bounds__(256) void aggfin(const ushort* __restrict__ G,
                                              const _Float16* __restrict__ R,
                                              const float* __restrict__ bias,
                                              const int* __restrict__ offsets,
                                              const int* __restrict__ counts,
                                              const int* __restrict__ sorted_src,
                                              const float* __restrict__ inv_cnt,
                                              ushort* __restrict__ xnext,
                                              float* __restrict__ outf, int n) {
    constexpr int PL = DOUT / 64;    // floats per lane: 8 (512) or 4 (256)
    int wave = threadIdx.x >> 6;
    int lane = threadIdx.x & 63;
    int node = blockIdx.x * 4 + wave;
    if (node >= n) return;
    int start = offsets[node];
    int cnt   = counts[node];
    float inv = inv_cnt[node];

    float acc[PL];
#pragma unroll
    for (int k = 0; k < PL; k++) acc[k] = 0.f;

    if constexpr (DOUT == 512) {
        const uint* gp = (const uint*)G + lane * 4;   // row stride 256 uints
#define ACC8(v) do { \
        acc[0] += blo(v.x); acc[1] += bhi(v.x); \
        acc[2] += blo(v.y); acc[3] += bhi(v.y); \
        acc[4] += blo(v.z); acc[5] += bhi(v.z); \
        acc[6] += blo(v.w); acc[7] += bhi(v.w); } while (0)
        int e = 0;
        for (; e + 8 <= cnt; e += 8) {
            uint4 vv[8];
#pragma unroll
            for (int u = 0; u < 8; u++) {
                int s0 = sorted_src[start + e + u];
                vv[u] = *(const uint4*)(gp + (size_t)s0 * 256);
            }
#pragma unroll
            for (int u = 0; u < 8; u++) ACC8(vv[u]);
        }
        for (; e < cnt; e++) {
            int s0 = sorted_src[start + e];
            uint4 v0 = *(const uint4*)(gp + (size_t)s0 * 256);
            ACC8(v0);
        }
#undef ACC8
    } else {
        const uint* gp = (const uint*)G + lane * 2;   // row stride 128 uints
#define ACC4(v) do { \
        acc[0] += blo(v.x); acc[1] += bhi(v.x); \
        acc[2] += blo(v.y); acc[3] += bhi(v.y); } while (0)
        int e = 0;
        for (; e + 8 <= cnt; e += 8) {
            uint2 vv[8];
#pragma unroll
            for (int u = 0; u < 8; u++) {
                int s0 = sorted_src[start + e + u];
                vv[u] = *(const uint2*)(gp + (size_t)s0 * 128);
            }
#pragma unroll
            for (int u = 0; u < 8; u++) ACC4(vv[u]);
        }
        for (; e < cnt; e++) {
            int s0 = sorted_src[start + e];
            uint2 v0 = *(const uint2*)(gp + (size_t)s0 * 128);
            ACC4(v0);
        }
#undef ACC4
    }

    float v[PL];
    const _Float16* Rp = R + (size_t)node * DOUT + lane * PL;
    const float* Bp = bias + lane * PL;
    if constexpr (PL == 8) {
        h16x8 hv = *(const h16x8*)Rp;
#pragma unroll
        for (int k = 0; k < PL; k += 4) {
            float4 b4 = *(const float4*)(Bp + k);
            v[k + 0] = acc[k + 0] * inv + (float)hv[k + 0] + b4.x;
            v[k + 1] = acc[k + 1] * inv + (float)hv[k + 1] + b4.y;
            v[k + 2] = acc[k + 2] * inv + (float)hv[k + 2] + b4.z;
            v[k + 3] = acc[k + 3] * inv + (float)hv[k + 3] + b4.w;
        }
    } else {
        h16x4 hv = *(const h16x4*)Rp;
#pragma unroll
        for (int k = 0; k < PL; k += 4) {
            float4 b4 = *(const float4*)(Bp + k);
            v[k + 0] = acc[k + 0] * inv + (float)hv[k + 0] + b4.x;
            v[k + 1] = acc[k + 1] * inv + (float)hv[k + 1] + b4.y;
            v[k + 2] = acc[k + 2] * inv + (float)hv[k + 2] + b4.z;
            v[k + 3] = acc[k + 3] * inv + (float)hv[k + 3] + b4.w;
        }
    }

    float ss = 0.f;
#pragma unroll
    for (int k = 0; k < PL; k++) ss += v[k] * v[k];
#pragma unroll
    for (int m = 32; m >= 1; m >>= 1) ss += __shfl_xor(ss, m, 64);
    float scale = 1.0f / fmaxf(sqrtf(ss), 1e-12f);

    if constexpr (FINAL) {
        float* Op = outf + (size_t)node * DOUT + lane * PL;
#pragma unroll
        for (int k = 0; k < PL; k += 4) {
            float4 o;
            o.x = fmaxf(v[k + 0] * scale, 0.f);
            o.y = fmaxf(v[k + 1] * scale, 0.f);
            o.z = fmaxf(v[k + 2] * scale, 0.f);
            o.w = fmaxf(v[k + 3] * scale, 0.f);
            *(float4*)(Op + k) = o;
        }
    } else {
        // DOUT == 512: 8 bf16 = 16B per lane
        uint4 o;
        float r0 = fmaxf(v[0] * scale, 0.f), r1 = fmaxf(v[1] * scale, 0.f);
        float r2 = fmaxf(v[2] * scale, 0.f), r3 = fmaxf(v[3] * scale, 0.f);
        float r4 = fmaxf(v[4] * scale, 0.f), r5 = fmaxf(v[5] * scale, 0.f);
        float r6 = fmaxf(v[6] * scale, 0.f), r7 = fmaxf(v[7] * scale, 0.f);
        o.x = packbf(r0, r1); o.y = packbf(r2, r3);
        o.z = packbf(r4, r5); o.w = packbf(r6, r7);
        *(uint4*)(xnext + (size_t)node * 512 + lane * 8) = o;
    }
}

// ---------------------------------------------------------------------------
extern "C" void kernel_launch(void* const* d_in, const int* in_sizes, int n_in,
                              void* d_out, int out_size, void* d_ws, size_t ws_size,
                              hipStream_t stream) {
    const float* x    = (const float*)d_in[0];
    const int*   edge = (const int*)d_in[1];     // [2, E]: src row then dst row
    const float* Wl0  = (const float*)d_in[2];
    const float* b0   = (const float*)d_in[3];
    const float* Wr0  = (const float*)d_in[4];
    const float* Wl1  = (const float*)d_in[5];
    const float* b1   = (const float*)d_in[6];
    const float* Wr1  = (const float*)d_in[7];
    const float* Wl2  = (const float*)d_in[8];
    const float* b2   = (const float*)d_in[9];
    const float* Wr2  = (const float*)d_in[10];

    const int E = in_sizes[1] / 2;

    // Workspace layout (bytes), all 256-aligned
    char* ws = (char*)d_ws;
    int*      counts  = (int*)(ws + 0);              // 40000
    int*      offsets = (int*)(ws + 40960);
    int*      cursor  = (int*)(ws + 81920);
    float*    invc    = (float*)(ws + 122880);
    int*      sorted  = (int*)(ws + 163840);         // 640000
    ushort*   Wc0     = (ushort*)(ws + 819200);      // 1048576
    ushort*   Wc1     = (ushort*)(ws + 1867776);     // 1048576
    ushort*   Wc2     = (ushort*)(ws + 2916352);     // 524288
    ushort*   xbuf    = (ushort*)(ws + 3440640);     // 10240000
    ushort*   Gbuf    = (ushort*)(ws + 13680640);    // 10240000
    _Float16* Rbuf    = (_Float16*)(ws + 23920640);  // 10240000
    int*      lpref   = (int*)(ws + 34160640);       // 40960
    int*      bsum    = (int*)(ws + 34201600);       // 256
    // end: 34201856 bytes

    // ---- bf16 conversions + counts zeroing (single fused launch, first) ----
    cvt_all<<<(1610180 + 255) / 256, 256, 0, stream>>>(x, Wl0, Wr0, Wl1, Wr1, Wl2, Wr2,
                                                       xbuf, Wc0, Wc1, Wc2, counts);

    // ---- CSR build (parallel hierarchical scan) ----
    const int nsb = (NN + 255) / 256;   // 40 scan blocks
    count_dst<<<(E + 255) / 256, 256, 0, stream>>>(edge + E, counts, E);
    scan_local<<<nsb, 256, 0, stream>>>(counts, lpref, bsum, NN);
    scan_apply<<<nsb, 256, 0, stream>>>(counts, lpref, bsum, offsets, cursor, invc, NN);
    scatter_edges<<<(E + 255) / 256, 256, 0, stream>>>(edge, edge + E, cursor, sorted, E);

    const int gyM = (NN + 127) / 128;   // 79
    const int gb  = (NN + 3) / 4;       // 2500

    // ---- layer 0 ----
    gemm_split<<<dim3(8, gyM), 256, 0, stream>>>(xbuf, Wc0, Gbuf, Rbuf, NN, 512);
    aggfin<512, false><<<gb, 256, 0, stream>>>(Gbuf, Rbuf, b0, offsets, counts,
                                               sorted, invc, xbuf, nullptr, NN);
    // ---- layer 1 ----
    gemm_split<<<dim3(8, gyM), 256, 0, stream>>>(xbuf, Wc1, Gbuf, Rbuf, NN, 512);
    aggfin<512, false><<<gb, 256, 0, stream>>>(Gbuf, Rbuf, b1, offsets, counts,
                                               sorted, invc, xbuf, nullptr, NN);
    // ---- layer 2 (dout=256, final fp32 out) ----
    gemm_split<<<dim3(4, gyM), 256, 0, stream>>>(xbuf, Wc2, Gbuf, Rbuf, NN, 256);
    aggfin<256, true><<<gb, 256, 0, stream>>>(Gbuf, Rbuf, b2, offsets, counts,
                                              sorted, invc, nullptr, (float*)d_out, NN);
}